// Round 8
// baseline (6968.309 us; speedup 1.0000x reference)
//
#include <hip/hip_runtime.h>
#include <hip/hip_bf16.h>

// ---------------------------------------------------------------------------
// Hetero-GNN forward: 6 SAGEConv (mean aggr, L2-norm) + 3 GCNConv + 3 BN.
// Round 8: kill the 20 G/s device-atomic ceiling. Two-phase bin aggregation:
//  phase1 bin_edges: LDS-count per 100-dst bin, ~1000 global atomics/block
//    (256k total vs 2M), compact packed (src|dl<<17) writes per bin.
//  phase2 bin_agg: 1 block/bin, 26KB LDS f32 accumulator, ds_add_f32 atomics
//    (per-CU, not fabric-limited), 4-deep float4 gather pipeline. Replaces
//    bucket_fill AND the perm-gather agg. SAGE deg in-LDS; GCN deg pre-pass.
// MFMA epilogues unchanged.
// ---------------------------------------------------------------------------

#define GRID   2048
#define BLK    256
#define DSTR   100    // dsts per bin
#define BCAP   3072   // bin capacity (mean 2000, sigma ~45 -> 23 sigma)
#define P1G    256    // phase-1 blocks
#define P1B    256    // phase-1 threads

typedef __attribute__((ext_vector_type(8))) short bf16x8;  // 8 bf16 (4 VGPR)
typedef __attribute__((ext_vector_type(4))) float f32x4;   // MFMA C/D frag

__device__ inline short f2bf(float f) {
  __hip_bfloat16 h = __float2bfloat16(f);
  return *reinterpret_cast<short*>(&h);
}

__device__ inline bf16x8 load_bf8(const float* p) {
  const float4 a = *(const float4*)p;
  const float4 b = *(const float4*)(p + 4);
  bf16x8 r;
  r[0] = f2bf(a.x); r[1] = f2bf(a.y); r[2] = f2bf(a.z); r[3] = f2bf(a.w);
  r[4] = f2bf(b.x); r[5] = f2bf(b.y); r[6] = f2bf(b.z); r[7] = f2bf(b.w);
  return r;
}

// B-fragment: lane holds W[kbase+j][col], j=0..7
__device__ inline bf16x8 load_wfrag(const float* W, int kbase, int col) {
  bf16x8 r;
#pragma unroll
  for (int j = 0; j < 8; ++j) r[j] = f2bf(W[(kbase + j) * 64 + col]);
  return r;
}

// ---- phase 1: bin edges by dst/DSTR, packed word = src | (dstlocal<<17) ---
__global__ __launch_bounds__(P1B) void bin_edges(
    const int* __restrict__ ei, int* __restrict__ bincur,
    int* __restrict__ binbuf, int E, int nbins) {
  __shared__ int cnt[1024];
  __shared__ int cur[1024];
  const int t = threadIdx.x;
  for (int i = t; i < nbins; i += P1B) cnt[i] = 0;
  __syncthreads();
  const int per = (E + gridDim.x - 1) / gridDim.x;
  const int e0 = blockIdx.x * per;
  const int e1 = min(e0 + per, E);
  for (int e = e0 + t; e < e1; e += P1B)
    atomicAdd(&cnt[ei[E + e] / DSTR], 1);
  __syncthreads();
  for (int i = t; i < nbins; i += P1B) {
    const int c = cnt[i];
    cur[i] = c ? atomicAdd(&bincur[i], c) : 0;
  }
  __syncthreads();
  for (int e = e0 + t; e < e1; e += P1B) {
    const int d = ei[E + e];
    const int s = ei[e];
    const int b = d / DSTR;
    const int pos = atomicAdd(&cur[b], 1);
    if (pos < BCAP) binbuf[(size_t)b * BCAP + pos] = s | ((d - b * DSTR) << 17);
  }
}

// ---- GCN degree pre-pass: per-bin LDS count -> global deg ----------------
__global__ __launch_bounds__(256) void deg_from_bins(
    const int* __restrict__ bincur, const int* __restrict__ binbuf,
    int* __restrict__ deg, int N) {
  __shared__ int sdeg[DSTR];
  const int bin = blockIdx.x;
  const int t = threadIdx.x;
  if (t < DSTR) sdeg[t] = 0;
  __syncthreads();
  const int m = min(bincur[bin], BCAP);
  const int* bb = binbuf + (size_t)bin * BCAP;
  for (int j = t; j < m; j += 256) atomicAdd(&sdeg[bb[j] >> 17], 1);
  __syncthreads();
  const int d0 = bin * DSTR;
  if (t < DSTR && d0 + t < N) deg[d0 + t] = sdeg[t];
}

// ---- phase 2: per-bin LDS accumulation -----------------------------------
// GCN=0: acc[dl] += x[src]; counts deg -> degout.
// GCN=1: acc[dl] += x[src] * rsqrt(deg[src]+1); deg read-only.
template <int GCN>
__global__ __launch_bounds__(512) void bin_agg(
    const float* __restrict__ x, const int* __restrict__ bincur,
    const int* __restrict__ binbuf, const int* __restrict__ deg,
    float* __restrict__ agg, int* __restrict__ degout, int N) {
  __shared__ float acc[DSTR * 64];
  __shared__ int sdeg[DSTR];
  const int t = threadIdx.x;
  for (int i = t; i < DSTR * 64; i += 512) acc[i] = 0.0f;
  if (t < DSTR) sdeg[t] = 0;
  __syncthreads();
  const int bin = blockIdx.x;
  const int m = min(bincur[bin], BCAP);
  const int* bb = binbuf + (size_t)bin * BCAP;
  const int lane = t & 63;
  const int w = t >> 6;       // 8 waves
  const int gid = lane >> 4;  // subgroup: 4 edges in flight
  const int cl = lane & 15;   // channel quad
  for (int j0 = w * 64; j0 < m; j0 += 8 * 64) {
    const int mm = min(m - j0, 64);
    int sv = 0, dlv = 0;
    float cs = 1.0f;
    if (lane < mm) {
      const int wd = bb[j0 + lane];
      sv = wd & 0x1FFFF;
      dlv = wd >> 17;
      if (GCN) cs = rsqrtf((float)deg[sv] + 1.0f);
      else atomicAdd(&sdeg[dlv], 1);
    }
    for (int k = 0; k < mm; k += 16) {
      float4 vs[4];
      float wsc[4];
      int dls[4];
#pragma unroll
      for (int tt = 0; tt < 4; ++tt) {
        const int i = k + tt * 4 + gid;
        const int ic = (i < mm) ? i : (mm - 1);
        const int sidx = __shfl(sv, ic, 64);
        dls[tt] = __shfl(dlv, ic, 64);
        const float c = GCN ? __shfl(cs, ic, 64) : 1.0f;
        wsc[tt] = (i < mm) ? c : 0.0f;
        vs[tt] = *(const float4*)(x + (size_t)sidx * 64 + (cl << 2));
      }
#pragma unroll
      for (int tt = 0; tt < 4; ++tt) {
        float* a = acc + dls[tt] * 64 + (cl << 2);
        atomicAdd(a + 0, vs[tt].x * wsc[tt]);
        atomicAdd(a + 1, vs[tt].y * wsc[tt]);
        atomicAdd(a + 2, vs[tt].z * wsc[tt]);
        atomicAdd(a + 3, vs[tt].w * wsc[tt]);
      }
    }
  }
  __syncthreads();
  const int d0 = bin * DSTR;
  for (int i = t; i < DSTR * 16; i += 512) {
    const int row = i >> 4;
    if (d0 + row < N)
      *(float4*)(agg + (size_t)(d0 + row) * 64 + (i & 15) * 4) =
          *(const float4*)(acc + i * 4);
  }
  if (!GCN && t < DSTR && d0 + t < N) degout[d0 + t] = sdeg[t];
}

// ---- fused MFMA epilogues -------------------------------------------------
// MFMA 16x16x32 bf16: A lane holds A[lane&15][8*(lane>>4)+j];
// C/D lane holds D[4*(lane>>4)+i][lane&15].

// SAGE: out = relu(l2norm((A/max(deg,1))@Wl + xdst@Wr + b))
template <int CD>
__global__ __launch_bounds__(256) void sage_ep(
    const float* __restrict__ agg, const int* __restrict__ deg,
    const float* __restrict__ xdst, const float* __restrict__ Wl,
    const float* __restrict__ bias, const float* __restrict__ Wr,
    float* __restrict__ out, int n) {
  const int lane = threadIdx.x & 63;
  const int lr   = lane & 15;
  const int kg   = lane >> 4;
  const int wid  = (blockIdx.x * 256 + threadIdx.x) >> 6;
  const int nw   = (gridDim.x * 256) >> 6;
  bf16x8 wl[2][4], wr[CD / 32][4];
#pragma unroll
  for (int ks = 0; ks < 2; ++ks)
#pragma unroll
    for (int t = 0; t < 4; ++t)
      wl[ks][t] = load_wfrag(Wl, ks * 32 + kg * 8, t * 16 + lr);
#pragma unroll
  for (int ks = 0; ks < CD / 32; ++ks)
#pragma unroll
    for (int t = 0; t < 4; ++t)
      wr[ks][t] = load_wfrag(Wr, ks * 32 + kg * 8, t * 16 + lr);
  const int ntiles = (n + 15) >> 4;
  for (int tile = wid; tile < ntiles; tile += nw) {
    const int r0 = tile << 4;
    const int ra = min(r0 + lr, n - 1);
    const float inva = 1.0f / fmaxf((float)deg[ra], 1.0f);
    f32x4 acc[4];
#pragma unroll
    for (int t = 0; t < 4; ++t) { acc[t][0]=0.f; acc[t][1]=0.f; acc[t][2]=0.f; acc[t][3]=0.f; }
#pragma unroll
    for (int ks = 0; ks < 2; ++ks) {
      const float* ap = agg + (size_t)ra * 64 + ks * 32 + kg * 8;
      const float4 a0 = *(const float4*)ap;
      const float4 a1 = *(const float4*)(ap + 4);
      bf16x8 af;
      af[0] = f2bf(a0.x * inva); af[1] = f2bf(a0.y * inva);
      af[2] = f2bf(a0.z * inva); af[3] = f2bf(a0.w * inva);
      af[4] = f2bf(a1.x * inva); af[5] = f2bf(a1.y * inva);
      af[6] = f2bf(a1.z * inva); af[7] = f2bf(a1.w * inva);
#pragma unroll
      for (int t = 0; t < 4; ++t)
        acc[t] = __builtin_amdgcn_mfma_f32_16x16x32_bf16(af, wl[ks][t], acc[t], 0, 0, 0);
    }
#pragma unroll
    for (int ks = 0; ks < CD / 32; ++ks) {
      const bf16x8 xf = load_bf8(xdst + (size_t)ra * CD + ks * 32 + kg * 8);
#pragma unroll
      for (int t = 0; t < 4; ++t)
        acc[t] = __builtin_amdgcn_mfma_f32_16x16x32_bf16(xf, wr[ks][t], acc[t], 0, 0, 0);
    }
#pragma unroll
    for (int t = 0; t < 4; ++t) {
      const float bv = bias[t * 16 + lr];
#pragma unroll
      for (int i = 0; i < 4; ++i) acc[t][i] += bv;
    }
    float ssi[4];
#pragma unroll
    for (int i = 0; i < 4; ++i) {
      float s = acc[0][i] * acc[0][i] + acc[1][i] * acc[1][i] +
                acc[2][i] * acc[2][i] + acc[3][i] * acc[3][i];
      s += __shfl_xor(s, 1, 64); s += __shfl_xor(s, 2, 64);
      s += __shfl_xor(s, 4, 64); s += __shfl_xor(s, 8, 64);
      ssi[i] = fmaxf(sqrtf(s), 1e-12f);
    }
#pragma unroll
    for (int t = 0; t < 4; ++t)
#pragma unroll
      for (int i = 0; i < 4; ++i) {
        const int r = r0 + kg * 4 + i;
        if (r < n) out[(size_t)r * 64 + t * 16 + lr] = fmaxf(acc[t][i] / ssi[i], 0.0f);
      }
  }
}

// GCN: v = relu((A*rsqrt(dd) + x/dd)@W + b), dd = deg+1; BN stats into stats
__global__ __launch_bounds__(256) void gcn_ep(
    const float* __restrict__ agg, const float* __restrict__ x,
    const int* __restrict__ deg, const float* __restrict__ W,
    const float* __restrict__ bias, float* __restrict__ v,
    float* __restrict__ stats, int n) {
  __shared__ float ssum[64], ssq[64];
  if (threadIdx.x < 64) { ssum[threadIdx.x] = 0.f; ssq[threadIdx.x] = 0.f; }
  __syncthreads();
  const int lane = threadIdx.x & 63;
  const int lr   = lane & 15;
  const int kg   = lane >> 4;
  const int wid  = (blockIdx.x * 256 + threadIdx.x) >> 6;
  const int nw   = (gridDim.x * 256) >> 6;
  bf16x8 wf[2][4];
#pragma unroll
  for (int ks = 0; ks < 2; ++ks)
#pragma unroll
    for (int t = 0; t < 4; ++t)
      wf[ks][t] = load_wfrag(W, ks * 32 + kg * 8, t * 16 + lr);
  float psum[4] = {0.f, 0.f, 0.f, 0.f}, psq[4] = {0.f, 0.f, 0.f, 0.f};
  const int ntiles = (n + 15) >> 4;
  for (int tile = wid; tile < ntiles; tile += nw) {
    const int r0 = tile << 4;
    const int ra = min(r0 + lr, n - 1);
    const float dd = (float)deg[ra] + 1.0f;
    const float ca = rsqrtf(dd);
    const float cb = 1.0f / dd;
    f32x4 acc[4];
#pragma unroll
    for (int t = 0; t < 4; ++t) { acc[t][0]=0.f; acc[t][1]=0.f; acc[t][2]=0.f; acc[t][3]=0.f; }
#pragma unroll
    for (int ks = 0; ks < 2; ++ks) {
      const float* ap = agg + (size_t)ra * 64 + ks * 32 + kg * 8;
      const float* xp = x   + (size_t)ra * 64 + ks * 32 + kg * 8;
      const float4 a0 = *(const float4*)ap;
      const float4 a1 = *(const float4*)(ap + 4);
      const float4 x0 = *(const float4*)xp;
      const float4 x1 = *(const float4*)(xp + 4);
      bf16x8 af;
      af[0] = f2bf(a0.x * ca + x0.x * cb); af[1] = f2bf(a0.y * ca + x0.y * cb);
      af[2] = f2bf(a0.z * ca + x0.z * cb); af[3] = f2bf(a0.w * ca + x0.w * cb);
      af[4] = f2bf(a1.x * ca + x1.x * cb); af[5] = f2bf(a1.y * ca + x1.y * cb);
      af[6] = f2bf(a1.z * ca + x1.z * cb); af[7] = f2bf(a1.w * ca + x1.w * cb);
#pragma unroll
      for (int t = 0; t < 4; ++t)
        acc[t] = __builtin_amdgcn_mfma_f32_16x16x32_bf16(af, wf[ks][t], acc[t], 0, 0, 0);
    }
#pragma unroll
    for (int t = 0; t < 4; ++t) {
      const float bv = bias[t * 16 + lr];
#pragma unroll
      for (int i = 0; i < 4; ++i) {
        const int r = r0 + kg * 4 + i;
        if (r < n) {
          const float val = fmaxf(acc[t][i] + bv, 0.0f);
          v[(size_t)r * 64 + t * 16 + lr] = val;
          psum[t] += val;
          psq[t]  += val * val;
        }
      }
    }
  }
#pragma unroll
  for (int t = 0; t < 4; ++t) {
    atomicAdd(&ssum[t * 16 + lr], psum[t]);
    atomicAdd(&ssq[t * 16 + lr], psq[t]);
  }
  __syncthreads();
  if (threadIdx.x < 64) {
    atomicAdd(&stats[threadIdx.x], ssum[threadIdx.x]);
    atomicAdd(&stats[64 + threadIdx.x], ssq[threadIdx.x]);
  }
}

// out = (v - mean) * rsqrt(var + 1e-5) * gam + bet
__global__ __launch_bounds__(BLK) void bn_apply(
    const float* __restrict__ v, const float* __restrict__ stats,
    const float* __restrict__ gam, const float* __restrict__ bet,
    float* __restrict__ out, int n) {
  __shared__ float sm[64], sr[64], sg[64], sbt[64];
  if (threadIdx.x < 64) {
    const float m   = stats[threadIdx.x] / (float)n;
    const float var = stats[64 + threadIdx.x] / (float)n - m * m;
    sm[threadIdx.x]  = m;
    sr[threadIdx.x]  = rsqrtf(var + 1e-5f);
    sg[threadIdx.x]  = gam[threadIdx.x];
    sbt[threadIdx.x] = bet[threadIdx.x];
  }
  __syncthreads();
  const int lane = threadIdx.x & 63;
  const int w    = threadIdx.x >> 6;
  for (int r = blockIdx.x * 4 + w; r < n; r += gridDim.x * 4) {
    out[(size_t)r * 64 + lane] =
        (v[(size_t)r * 64 + lane] - sm[lane]) * sr[lane] * sg[lane] + sbt[lane];
  }
}

extern "C" void kernel_launch(void* const* d_in, const int* in_sizes, int n_in,
                              void* d_out, int out_size, void* d_ws, size_t ws_size,
                              hipStream_t stream) {
  const float* game_x  = (const float*)d_in[0];
  const float* state_x = (const float*)d_in[1];
  const float* pc_x    = (const float*)d_in[2];
  const int* ei_vv  = (const int*)d_in[3];
  const int* ei_hvs = (const int*)d_in[4];
  const int* ei_hsv = (const int*)d_in[5];
  const int* ei_ivs = (const int*)d_in[6];
  const int* ei_isv = (const int*)d_in[7];
  const int* ei_ss  = (const int*)d_in[8];
  const int* ei_pp  = (const int*)d_in[9];
  const int* ei_ps  = (const int*)d_in[10];
  const int* ei_sp  = (const int*)d_in[11];
  const float* s_Wl[6], *s_b[6], *s_Wr[6];
  for (int i = 0; i < 6; ++i) {
    s_Wl[i] = (const float*)d_in[12 + 3 * i];
    s_b[i]  = (const float*)d_in[13 + 3 * i];
    s_Wr[i] = (const float*)d_in[14 + 3 * i];
  }
  const float* gcfg_W = (const float*)d_in[30];
  const float* gcfg_b = (const float*)d_in[31];
  const float* gpc_W  = (const float*)d_in[32];
  const float* gpc_b  = (const float*)d_in[33];
  const float* gst_W  = (const float*)d_in[34];
  const float* gst_b  = (const float*)d_in[35];
  const float* bncfg_g = (const float*)d_in[36];
  const float* bncfg_b = (const float*)d_in[37];
  const float* bnpc_g  = (const float*)d_in[38];
  const float* bnpc_b  = (const float*)d_in[39];
  const float* bnst_g  = (const float*)d_in[40];
  const float* bnst_b  = (const float*)d_in[41];

  const int N = in_sizes[1] / 64;   // nodes per type (100000)
  const int E = in_sizes[3] / 2;    // edges per relation (2000000)
  const int NBINS = (N + DSTR - 1) / DSTR;  // 1000

  const size_t nb = (size_t)N * 64;
  // workspace (~64 MB)
  float* A      = (float*)d_ws;               // nb: aggregated features
  float* X      = A + nb;                     // nb: rotating temp
  int*   DEG    = (int*)(X + nb);             // N degrees (reused per relation)
  int*   BINCUR = DEG + N;                    // NBINS cursors
  int*   BINBUF = BINCUR + NBINS;             // NBINS*BCAP packed edges
  float* STAT   = (float*)(BINBUF + (size_t)NBINS * BCAP);  // 128 BN stats

  float* out_s = (float*)d_out;               // f32 outputs; g/p double as temps
  float* out_g = out_s + nb;
  float* out_p = out_g + nb;

  auto build_bins = [&](const int* ei) {
    hipMemsetAsync(BINCUR, 0, NBINS * sizeof(int), stream);
    bin_edges<<<P1G, P1B, 0, stream>>>(ei, BINCUR, BINBUF, E, NBINS);
  };

  auto run_sage = [&](const int* ei, const float* xsrc, const float* xdst, int cd,
                      int wi, float* outbuf) {
    build_bins(ei);
    bin_agg<0><<<NBINS, 512, 0, stream>>>(xsrc, BINCUR, BINBUF, DEG, A, DEG, N);
    if (cd == 32)
      sage_ep<32><<<1024, 256, 0, stream>>>(A, DEG, xdst, s_Wl[wi], s_b[wi],
                                            s_Wr[wi], outbuf, N);
    else
      sage_ep<64><<<1024, 256, 0, stream>>>(A, DEG, xdst, s_Wl[wi], s_b[wi],
                                            s_Wr[wi], outbuf, N);
  };

  auto run_gcn_bn = [&](const int* ei, const float* x, const float* W, const float* b,
                        const float* bng, const float* bnb, float* vbuf,
                        float* outbuf) {
    build_bins(ei);
    deg_from_bins<<<NBINS, 256, 0, stream>>>(BINCUR, BINBUF, DEG, N);
    bin_agg<1><<<NBINS, 512, 0, stream>>>(x, BINCUR, BINBUF, DEG, A, DEG, N);
    hipMemsetAsync(STAT, 0, 128 * sizeof(float), stream);
    gcn_ep<<<1024, 256, 0, stream>>>(A, x, DEG, W, b, vbuf, STAT, N);
    bn_apply<<<GRID, BLK, 0, stream>>>(vbuf, STAT, bng, bnb, outbuf, N);
  };

  // ---- graph ----
  // g1 = relu(sage1(state->game))                      -> X
  run_sage(ei_hsv, state_x, game_x, 32, 0, X);
  // g2 = relu(sage2(state->g1))                        -> out_g
  run_sage(ei_isv, state_x, X, 64, 1, out_g);
  // g  = bn(relu(gcn(g2, v_v)))      v->X              -> out_g
  run_gcn_bn(ei_vv, out_g, gcfg_W, gcfg_b, bncfg_g, bncfg_b, X, out_g);
  // p1 = relu(sage3(state->pc))                        -> X
  run_sage(ei_sp, state_x, pc_x, 32, 2, X);
  // p  = bn(relu(gcn(p1, pc_pc)))    v->out_p (inpl)   -> out_p
  run_gcn_bn(ei_pp, X, gpc_W, gpc_b, bnpc_g, bnpc_b, out_p, out_p);
  // s1 = relu(sage4(g->state))                         -> X
  run_sage(ei_hvs, out_g, state_x, 64, 3, X);
  // s2 = relu(sage5(g->s1))                            -> out_s (scratch)
  run_sage(ei_ivs, out_g, X, 64, 4, out_s);
  // s3 = relu(sage6(p->s2))                            -> X
  run_sage(ei_ps, out_p, out_s, 64, 5, X);
  // s  = bn(relu(gcn(s3, s_s)))      v->out_s (inpl)   -> out_s
  run_gcn_bn(ei_ss, X, gst_W, gst_b, bnst_g, bnst_b, out_s, out_s);
}

// Round 9
// 1426.759 us; speedup vs baseline: 4.8840x; 4.8840x over previous
//
#include <hip/hip_runtime.h>
#include <hip/hip_bf16.h>

// ---------------------------------------------------------------------------
// Hetero-GNN forward: 6 SAGEConv (mean aggr, L2-norm) + 3 GCNConv + 3 BN.
// Round 9: fix round-8 regression (128M LDS f32 atomics). Keep cheap phase-1
// binning (256k global atomics); phase 2 = per-bin COUNTING SORT in LDS
// (~4k LDS int atomics/bin) -> contiguous per-dst runs -> register float4
// gather pipeline (round-7 proven). No bulk LDS-atomic accumulation, no
// global perm round-trip, no 20 G/s device-atomic ceiling.
// MFMA epilogues unchanged.
// ---------------------------------------------------------------------------

#define GRID   2048
#define BLK    256
#define DSTR   100    // dsts per bin
#define BCAP   3072   // bin capacity (mean 2000, sigma ~45)
#define P1G    256    // phase-1 blocks
#define P1B    256    // phase-1 threads

typedef __attribute__((ext_vector_type(8))) short bf16x8;  // 8 bf16 (4 VGPR)
typedef __attribute__((ext_vector_type(4))) float f32x4;   // MFMA C/D frag

__device__ inline short f2bf(float f) {
  __hip_bfloat16 h = __float2bfloat16(f);
  return *reinterpret_cast<short*>(&h);
}

__device__ inline bf16x8 load_bf8(const float* p) {
  const float4 a = *(const float4*)p;
  const float4 b = *(const float4*)(p + 4);
  bf16x8 r;
  r[0] = f2bf(a.x); r[1] = f2bf(a.y); r[2] = f2bf(a.z); r[3] = f2bf(a.w);
  r[4] = f2bf(b.x); r[5] = f2bf(b.y); r[6] = f2bf(b.z); r[7] = f2bf(b.w);
  return r;
}

// B-fragment: lane holds W[kbase+j][col], j=0..7
__device__ inline bf16x8 load_wfrag(const float* W, int kbase, int col) {
  bf16x8 r;
#pragma unroll
  for (int j = 0; j < 8; ++j) r[j] = f2bf(W[(kbase + j) * 64 + col]);
  return r;
}

// ---- phase 1: bin edges by dst/DSTR, packed word = src | (dstlocal<<17) ---
__global__ __launch_bounds__(P1B) void bin_edges(
    const int* __restrict__ ei, int* __restrict__ bincur,
    int* __restrict__ binbuf, int E, int nbins) {
  __shared__ int cnt[1024];
  __shared__ int cur[1024];
  const int t = threadIdx.x;
  for (int i = t; i < nbins; i += P1B) cnt[i] = 0;
  __syncthreads();
  const int per = (E + gridDim.x - 1) / gridDim.x;
  const int e0 = blockIdx.x * per;
  const int e1 = min(e0 + per, E);
  for (int e = e0 + t; e < e1; e += P1B)
    atomicAdd(&cnt[ei[E + e] / DSTR], 1);
  __syncthreads();
  for (int i = t; i < nbins; i += P1B) {
    const int c = cnt[i];
    cur[i] = c ? atomicAdd(&bincur[i], c) : 0;
  }
  __syncthreads();
  for (int e = e0 + t; e < e1; e += P1B) {
    const int d = ei[E + e];
    const int s = ei[e];
    const int b = d / DSTR;
    const int pos = atomicAdd(&cur[b], 1);
    if (pos < BCAP) binbuf[(size_t)b * BCAP + pos] = s | ((d - b * DSTR) << 17);
  }
}

// ---- GCN degree pre-pass: per-bin LDS count -> global deg ----------------
__global__ __launch_bounds__(256) void deg_from_bins(
    const int* __restrict__ bincur, const int* __restrict__ binbuf,
    int* __restrict__ deg, int N) {
  __shared__ int sdeg[DSTR];
  const int bin = blockIdx.x;
  const int t = threadIdx.x;
  if (t < DSTR) sdeg[t] = 0;
  __syncthreads();
  const int m = min(bincur[bin], BCAP);
  const int* bb = binbuf + (size_t)bin * BCAP;
  for (int j = t; j < m; j += 256) atomicAdd(&sdeg[bb[j] >> 17], 1);
  __syncthreads();
  const int d0 = bin * DSTR;
  if (t < DSTR && d0 + t < N) deg[d0 + t] = sdeg[t];
}

// ---- phase 2: counting-sort by dl in LDS, then per-dst register gather ----
// GCN=0: agg[d] = sum x[src]; writes deg[d].  GCN=1: agg[d] = sum
// x[src]*rsqrt(deg[src]+1); deg read-only.
template <int GCN>
__global__ __launch_bounds__(512) void bin_sort_agg(
    const float* __restrict__ x, const int* __restrict__ bincur,
    const int* __restrict__ binbuf, const int* __restrict__ deg,
    float* __restrict__ agg, int* __restrict__ degout, int N) {
  __shared__ int scnt[DSTR];
  __shared__ int soff[DSTR + 1];
  __shared__ int scur[DSTR];
  __shared__ int sorted[BCAP];   // 12 KB: src indices grouped by dl
  const int t = threadIdx.x;
  const int bin = blockIdx.x;
  const int d0 = bin * DSTR;
  if (t < DSTR) scnt[t] = 0;
  __syncthreads();
  const int m = min(bincur[bin], BCAP);
  const int* bb = binbuf + (size_t)bin * BCAP;
  // count
  for (int j = t; j < m; j += 512) atomicAdd(&scnt[bb[j] >> 17], 1);
  __syncthreads();
  // exclusive prefix (serial, 100 elems)
  if (t == 0) {
    int run = 0;
    for (int i = 0; i < DSTR; ++i) { soff[i] = run; run += scnt[i]; }
    soff[DSTR] = run;
  }
  __syncthreads();
  if (t < DSTR) scur[t] = soff[t];
  if (!GCN && t < DSTR && d0 + t < N) degout[d0 + t] = scnt[t];
  __syncthreads();
  // scatter into sorted order
  for (int j = t; j < m; j += 512) {
    const int wd = bb[j];
    const int pos = atomicAdd(&scur[wd >> 17], 1);
    sorted[pos] = wd & 0x1FFFF;
  }
  __syncthreads();
  // aggregate: one wave per dl (8 waves round-robin)
  const int lane = t & 63;
  const int w    = t >> 6;
  const int gid  = lane >> 4;   // 4 edges in flight
  const int cl   = lane & 15;   // channel quad
  for (int dl = w; dl < DSTR; dl += 8) {
    if (d0 + dl >= N) break;
    const int beg = soff[dl];
    const int cnt = scnt[dl];
    float px = 0.f, py = 0.f, pz = 0.f, pw = 0.f;
    for (int j0 = 0; j0 < cnt; j0 += 64) {
      const int mm = min(cnt - j0, 64);
      int sv = 0; float cs = 1.0f;
      if (lane < mm) {
        sv = sorted[beg + j0 + lane];
        if (GCN) cs = rsqrtf((float)deg[sv] + 1.0f);
      }
      for (int k = 0; k < mm; k += 16) {
        float4 vs[4];
        float wsc[4];
#pragma unroll
        for (int tt = 0; tt < 4; ++tt) {
          const int i = k + tt * 4 + gid;
          const int ic = (i < mm) ? i : (mm - 1);
          const int sidx = __shfl(sv, ic, 64);
          const float c = GCN ? __shfl(cs, ic, 64) : 1.0f;
          wsc[tt] = (i < mm) ? c : 0.0f;
          vs[tt] = *(const float4*)(x + (size_t)sidx * 64 + (cl << 2));
        }
#pragma unroll
        for (int tt = 0; tt < 4; ++tt) {
          px += vs[tt].x * wsc[tt];
          py += vs[tt].y * wsc[tt];
          pz += vs[tt].z * wsc[tt];
          pw += vs[tt].w * wsc[tt];
        }
      }
    }
    px += __shfl_xor(px, 16, 64); px += __shfl_xor(px, 32, 64);
    py += __shfl_xor(py, 16, 64); py += __shfl_xor(py, 32, 64);
    pz += __shfl_xor(pz, 16, 64); pz += __shfl_xor(pz, 32, 64);
    pw += __shfl_xor(pw, 16, 64); pw += __shfl_xor(pw, 32, 64);
    if (gid == 0) {
      float4 o; o.x = px; o.y = py; o.z = pz; o.w = pw;
      *(float4*)(agg + (size_t)(d0 + dl) * 64 + (cl << 2)) = o;
    }
  }
}

// ---- fused MFMA epilogues -------------------------------------------------
// MFMA 16x16x32 bf16: A lane holds A[lane&15][8*(lane>>4)+j];
// C/D lane holds D[4*(lane>>4)+i][lane&15].

// SAGE: out = relu(l2norm((A/max(deg,1))@Wl + xdst@Wr + b))
template <int CD>
__global__ __launch_bounds__(256) void sage_ep(
    const float* __restrict__ agg, const int* __restrict__ deg,
    const float* __restrict__ xdst, const float* __restrict__ Wl,
    const float* __restrict__ bias, const float* __restrict__ Wr,
    float* __restrict__ out, int n) {
  const int lane = threadIdx.x & 63;
  const int lr   = lane & 15;
  const int kg   = lane >> 4;
  const int wid  = (blockIdx.x * 256 + threadIdx.x) >> 6;
  const int nw   = (gridDim.x * 256) >> 6;
  bf16x8 wl[2][4], wr[CD / 32][4];
#pragma unroll
  for (int ks = 0; ks < 2; ++ks)
#pragma unroll
    for (int t = 0; t < 4; ++t)
      wl[ks][t] = load_wfrag(Wl, ks * 32 + kg * 8, t * 16 + lr);
#pragma unroll
  for (int ks = 0; ks < CD / 32; ++ks)
#pragma unroll
    for (int t = 0; t < 4; ++t)
      wr[ks][t] = load_wfrag(Wr, ks * 32 + kg * 8, t * 16 + lr);
  const int ntiles = (n + 15) >> 4;
  for (int tile = wid; tile < ntiles; tile += nw) {
    const int r0 = tile << 4;
    const int ra = min(r0 + lr, n - 1);
    const float inva = 1.0f / fmaxf((float)deg[ra], 1.0f);
    f32x4 acc[4];
#pragma unroll
    for (int t = 0; t < 4; ++t) { acc[t][0]=0.f; acc[t][1]=0.f; acc[t][2]=0.f; acc[t][3]=0.f; }
#pragma unroll
    for (int ks = 0; ks < 2; ++ks) {
      const float* ap = agg + (size_t)ra * 64 + ks * 32 + kg * 8;
      const float4 a0 = *(const float4*)ap;
      const float4 a1 = *(const float4*)(ap + 4);
      bf16x8 af;
      af[0] = f2bf(a0.x * inva); af[1] = f2bf(a0.y * inva);
      af[2] = f2bf(a0.z * inva); af[3] = f2bf(a0.w * inva);
      af[4] = f2bf(a1.x * inva); af[5] = f2bf(a1.y * inva);
      af[6] = f2bf(a1.z * inva); af[7] = f2bf(a1.w * inva);
#pragma unroll
      for (int t = 0; t < 4; ++t)
        acc[t] = __builtin_amdgcn_mfma_f32_16x16x32_bf16(af, wl[ks][t], acc[t], 0, 0, 0);
    }
#pragma unroll
    for (int ks = 0; ks < CD / 32; ++ks) {
      const bf16x8 xf = load_bf8(xdst + (size_t)ra * CD + ks * 32 + kg * 8);
#pragma unroll
      for (int t = 0; t < 4; ++t)
        acc[t] = __builtin_amdgcn_mfma_f32_16x16x32_bf16(xf, wr[ks][t], acc[t], 0, 0, 0);
    }
#pragma unroll
    for (int t = 0; t < 4; ++t) {
      const float bv = bias[t * 16 + lr];
#pragma unroll
      for (int i = 0; i < 4; ++i) acc[t][i] += bv;
    }
    float ssi[4];
#pragma unroll
    for (int i = 0; i < 4; ++i) {
      float s = acc[0][i] * acc[0][i] + acc[1][i] * acc[1][i] +
                acc[2][i] * acc[2][i] + acc[3][i] * acc[3][i];
      s += __shfl_xor(s, 1, 64); s += __shfl_xor(s, 2, 64);
      s += __shfl_xor(s, 4, 64); s += __shfl_xor(s, 8, 64);
      ssi[i] = fmaxf(sqrtf(s), 1e-12f);
    }
#pragma unroll
    for (int t = 0; t < 4; ++t)
#pragma unroll
      for (int i = 0; i < 4; ++i) {
        const int r = r0 + kg * 4 + i;
        if (r < n) out[(size_t)r * 64 + t * 16 + lr] = fmaxf(acc[t][i] / ssi[i], 0.0f);
      }
  }
}

// GCN: v = relu((A*rsqrt(dd) + x/dd)@W + b), dd = deg+1; BN stats into stats
__global__ __launch_bounds__(256) void gcn_ep(
    const float* __restrict__ agg, const float* __restrict__ x,
    const int* __restrict__ deg, const float* __restrict__ W,
    const float* __restrict__ bias, float* __restrict__ v,
    float* __restrict__ stats, int n) {
  __shared__ float ssum[64], ssq[64];
  if (threadIdx.x < 64) { ssum[threadIdx.x] = 0.f; ssq[threadIdx.x] = 0.f; }
  __syncthreads();
  const int lane = threadIdx.x & 63;
  const int lr   = lane & 15;
  const int kg   = lane >> 4;
  const int wid  = (blockIdx.x * 256 + threadIdx.x) >> 6;
  const int nw   = (gridDim.x * 256) >> 6;
  bf16x8 wf[2][4];
#pragma unroll
  for (int ks = 0; ks < 2; ++ks)
#pragma unroll
    for (int t = 0; t < 4; ++t)
      wf[ks][t] = load_wfrag(W, ks * 32 + kg * 8, t * 16 + lr);
  float psum[4] = {0.f, 0.f, 0.f, 0.f}, psq[4] = {0.f, 0.f, 0.f, 0.f};
  const int ntiles = (n + 15) >> 4;
  for (int tile = wid; tile < ntiles; tile += nw) {
    const int r0 = tile << 4;
    const int ra = min(r0 + lr, n - 1);
    const float dd = (float)deg[ra] + 1.0f;
    const float ca = rsqrtf(dd);
    const float cb = 1.0f / dd;
    f32x4 acc[4];
#pragma unroll
    for (int t = 0; t < 4; ++t) { acc[t][0]=0.f; acc[t][1]=0.f; acc[t][2]=0.f; acc[t][3]=0.f; }
#pragma unroll
    for (int ks = 0; ks < 2; ++ks) {
      const float* ap = agg + (size_t)ra * 64 + ks * 32 + kg * 8;
      const float* xp = x   + (size_t)ra * 64 + ks * 32 + kg * 8;
      const float4 a0 = *(const float4*)ap;
      const float4 a1 = *(const float4*)(ap + 4);
      const float4 x0 = *(const float4*)xp;
      const float4 x1 = *(const float4*)(xp + 4);
      bf16x8 af;
      af[0] = f2bf(a0.x * ca + x0.x * cb); af[1] = f2bf(a0.y * ca + x0.y * cb);
      af[2] = f2bf(a0.z * ca + x0.z * cb); af[3] = f2bf(a0.w * ca + x0.w * cb);
      af[4] = f2bf(a1.x * ca + x1.x * cb); af[5] = f2bf(a1.y * ca + x1.y * cb);
      af[6] = f2bf(a1.z * ca + x1.z * cb); af[7] = f2bf(a1.w * ca + x1.w * cb);
#pragma unroll
      for (int t = 0; t < 4; ++t)
        acc[t] = __builtin_amdgcn_mfma_f32_16x16x32_bf16(af, wf[ks][t], acc[t], 0, 0, 0);
    }
#pragma unroll
    for (int t = 0; t < 4; ++t) {
      const float bv = bias[t * 16 + lr];
#pragma unroll
      for (int i = 0; i < 4; ++i) {
        const int r = r0 + kg * 4 + i;
        if (r < n) {
          const float val = fmaxf(acc[t][i] + bv, 0.0f);
          v[(size_t)r * 64 + t * 16 + lr] = val;
          psum[t] += val;
          psq[t]  += val * val;
        }
      }
    }
  }
#pragma unroll
  for (int t = 0; t < 4; ++t) {
    atomicAdd(&ssum[t * 16 + lr], psum[t]);
    atomicAdd(&ssq[t * 16 + lr], psq[t]);
  }
  __syncthreads();
  if (threadIdx.x < 64) {
    atomicAdd(&stats[threadIdx.x], ssum[threadIdx.x]);
    atomicAdd(&stats[64 + threadIdx.x], ssq[threadIdx.x]);
  }
}

// out = (v - mean) * rsqrt(var + 1e-5) * gam + bet
__global__ __launch_bounds__(BLK) void bn_apply(
    const float* __restrict__ v, const float* __restrict__ stats,
    const float* __restrict__ gam, const float* __restrict__ bet,
    float* __restrict__ out, int n) {
  __shared__ float sm[64], sr[64], sg[64], sbt[64];
  if (threadIdx.x < 64) {
    const float m   = stats[threadIdx.x] / (float)n;
    const float var = stats[64 + threadIdx.x] / (float)n - m * m;
    sm[threadIdx.x]  = m;
    sr[threadIdx.x]  = rsqrtf(var + 1e-5f);
    sg[threadIdx.x]  = gam[threadIdx.x];
    sbt[threadIdx.x] = bet[threadIdx.x];
  }
  __syncthreads();
  const int lane = threadIdx.x & 63;
  const int w    = threadIdx.x >> 6;
  for (int r = blockIdx.x * 4 + w; r < n; r += gridDim.x * 4) {
    out[(size_t)r * 64 + lane] =
        (v[(size_t)r * 64 + lane] - sm[lane]) * sr[lane] * sg[lane] + sbt[lane];
  }
}

extern "C" void kernel_launch(void* const* d_in, const int* in_sizes, int n_in,
                              void* d_out, int out_size, void* d_ws, size_t ws_size,
                              hipStream_t stream) {
  const float* game_x  = (const float*)d_in[0];
  const float* state_x = (const float*)d_in[1];
  const float* pc_x    = (const float*)d_in[2];
  const int* ei_vv  = (const int*)d_in[3];
  const int* ei_hvs = (const int*)d_in[4];
  const int* ei_hsv = (const int*)d_in[5];
  const int* ei_ivs = (const int*)d_in[6];
  const int* ei_isv = (const int*)d_in[7];
  const int* ei_ss  = (const int*)d_in[8];
  const int* ei_pp  = (const int*)d_in[9];
  const int* ei_ps  = (const int*)d_in[10];
  const int* ei_sp  = (const int*)d_in[11];
  const float* s_Wl[6], *s_b[6], *s_Wr[6];
  for (int i = 0; i < 6; ++i) {
    s_Wl[i] = (const float*)d_in[12 + 3 * i];
    s_b[i]  = (const float*)d_in[13 + 3 * i];
    s_Wr[i] = (const float*)d_in[14 + 3 * i];
  }
  const float* gcfg_W = (const float*)d_in[30];
  const float* gcfg_b = (const float*)d_in[31];
  const float* gpc_W  = (const float*)d_in[32];
  const float* gpc_b  = (const float*)d_in[33];
  const float* gst_W  = (const float*)d_in[34];
  const float* gst_b  = (const float*)d_in[35];
  const float* bncfg_g = (const float*)d_in[36];
  const float* bncfg_b = (const float*)d_in[37];
  const float* bnpc_g  = (const float*)d_in[38];
  const float* bnpc_b  = (const float*)d_in[39];
  const float* bnst_g  = (const float*)d_in[40];
  const float* bnst_b  = (const float*)d_in[41];

  const int N = in_sizes[1] / 64;   // nodes per type (100000)
  const int E = in_sizes[3] / 2;    // edges per relation (2000000)
  const int NBINS = (N + DSTR - 1) / DSTR;  // 1000

  const size_t nb = (size_t)N * 64;
  // workspace (~64 MB)
  float* A      = (float*)d_ws;               // nb: aggregated features
  float* X      = A + nb;                     // nb: rotating temp
  int*   DEG    = (int*)(X + nb);             // N degrees (reused per relation)
  int*   BINCUR = DEG + N;                    // NBINS cursors
  int*   BINBUF = BINCUR + NBINS;             // NBINS*BCAP packed edges
  float* STAT   = (float*)(BINBUF + (size_t)NBINS * BCAP);  // 128 BN stats

  float* out_s = (float*)d_out;               // f32 outputs; g/p double as temps
  float* out_g = out_s + nb;
  float* out_p = out_g + nb;

  auto build_bins = [&](const int* ei) {
    hipMemsetAsync(BINCUR, 0, NBINS * sizeof(int), stream);
    bin_edges<<<P1G, P1B, 0, stream>>>(ei, BINCUR, BINBUF, E, NBINS);
  };

  auto run_sage = [&](const int* ei, const float* xsrc, const float* xdst, int cd,
                      int wi, float* outbuf) {
    build_bins(ei);
    bin_sort_agg<0><<<NBINS, 512, 0, stream>>>(xsrc, BINCUR, BINBUF, DEG, A, DEG, N);
    if (cd == 32)
      sage_ep<32><<<1024, 256, 0, stream>>>(A, DEG, xdst, s_Wl[wi], s_b[wi],
                                            s_Wr[wi], outbuf, N);
    else
      sage_ep<64><<<1024, 256, 0, stream>>>(A, DEG, xdst, s_Wl[wi], s_b[wi],
                                            s_Wr[wi], outbuf, N);
  };

  auto run_gcn_bn = [&](const int* ei, const float* x, const float* W, const float* b,
                        const float* bng, const float* bnb, float* vbuf,
                        float* outbuf) {
    build_bins(ei);
    deg_from_bins<<<NBINS, 256, 0, stream>>>(BINCUR, BINBUF, DEG, N);
    bin_sort_agg<1><<<NBINS, 512, 0, stream>>>(x, BINCUR, BINBUF, DEG, A, DEG, N);
    hipMemsetAsync(STAT, 0, 128 * sizeof(float), stream);
    gcn_ep<<<1024, 256, 0, stream>>>(A, x, DEG, W, b, vbuf, STAT, N);
    bn_apply<<<GRID, BLK, 0, stream>>>(vbuf, STAT, bng, bnb, outbuf, N);
  };

  // ---- graph ----
  // g1 = relu(sage1(state->game))                      -> X
  run_sage(ei_hsv, state_x, game_x, 32, 0, X);
  // g2 = relu(sage2(state->g1))                        -> out_g
  run_sage(ei_isv, state_x, X, 64, 1, out_g);
  // g  = bn(relu(gcn(g2, v_v)))      v->X              -> out_g
  run_gcn_bn(ei_vv, out_g, gcfg_W, gcfg_b, bncfg_g, bncfg_b, X, out_g);
  // p1 = relu(sage3(state->pc))                        -> X
  run_sage(ei_sp, state_x, pc_x, 32, 2, X);
  // p  = bn(relu(gcn(p1, pc_pc)))    v->out_p (inpl)   -> out_p
  run_gcn_bn(ei_pp, X, gpc_W, gpc_b, bnpc_g, bnpc_b, out_p, out_p);
  // s1 = relu(sage4(g->state))                         -> X
  run_sage(ei_hvs, out_g, state_x, 64, 3, X);
  // s2 = relu(sage5(g->s1))                            -> out_s (scratch)
  run_sage(ei_ivs, out_g, X, 64, 4, out_s);
  // s3 = relu(sage6(p->s2))                            -> X
  run_sage(ei_ps, out_p, out_s, 64, 5, X);
  // s  = bn(relu(gcn(s3, s_s)))      v->out_s (inpl)   -> out_s
  run_gcn_bn(ei_ss, X, gst_W, gst_b, bnst_g, bnst_b, out_s, out_s);
}

// Round 10
// 1240.011 us; speedup vs baseline: 5.6196x; 1.1506x over previous
//
#include <hip/hip_runtime.h>
#include <hip/hip_bf16.h>

// ---------------------------------------------------------------------------
// Hetero-GNN forward: 6 SAGEConv (mean aggr, L2-norm) + 3 GCNConv + 3 BN.
// Round 10: bf16 gather. All gather-source tables are kept in bf16 (state_x
// converted once; conv outputs dual-written by the epilogues), halving the
// random-gather bytes (256->128 B/row). Aggregation still accumulates f32 in
// registers. Structure otherwise = round 9 (bin_edges + per-bin counting
// sort + register gather; MFMA epilogues).
// ---------------------------------------------------------------------------

#define GRID   2048
#define BLK    256
#define DSTR   100    // dsts per bin
#define BCAP   3072   // bin capacity (mean 2000)
#define P1G    256    // phase-1 blocks
#define P1B    256    // phase-1 threads

typedef __attribute__((ext_vector_type(8))) short bf16x8;          // MFMA A/B
typedef __attribute__((ext_vector_type(4))) float f32x4;           // MFMA C/D
typedef __attribute__((ext_vector_type(8))) unsigned short u16x8;  // bf16 row oct

__device__ inline short f2bf(float f) {
  __hip_bfloat16 h = __float2bfloat16(f);
  return *reinterpret_cast<short*>(&h);
}

__device__ inline float bf2f(unsigned short u) {
  union { unsigned int i; float f; } x;
  x.i = ((unsigned int)u) << 16;
  return x.f;
}

__device__ inline bf16x8 load_bf8(const float* p) {
  const float4 a = *(const float4*)p;
  const float4 b = *(const float4*)(p + 4);
  bf16x8 r;
  r[0] = f2bf(a.x); r[1] = f2bf(a.y); r[2] = f2bf(a.z); r[3] = f2bf(a.w);
  r[4] = f2bf(b.x); r[5] = f2bf(b.y); r[6] = f2bf(b.z); r[7] = f2bf(b.w);
  return r;
}

// B-fragment: lane holds W[kbase+j][col], j=0..7
__device__ inline bf16x8 load_wfrag(const float* W, int kbase, int col) {
  bf16x8 r;
#pragma unroll
  for (int j = 0; j < 8; ++j) r[j] = f2bf(W[(kbase + j) * 64 + col]);
  return r;
}

// ---- f32 -> bf16 table conversion (for gather sources) --------------------
__global__ __launch_bounds__(256) void cvt_bf16(
    const float* __restrict__ in, unsigned short* __restrict__ out, int n8) {
  for (int i = blockIdx.x * 256 + threadIdx.x; i < n8; i += gridDim.x * 256) {
    const float4 a = *(const float4*)(in + (size_t)i * 8);
    const float4 b = *(const float4*)(in + (size_t)i * 8 + 4);
    u16x8 r;
    r[0] = (unsigned short)f2bf(a.x); r[1] = (unsigned short)f2bf(a.y);
    r[2] = (unsigned short)f2bf(a.z); r[3] = (unsigned short)f2bf(a.w);
    r[4] = (unsigned short)f2bf(b.x); r[5] = (unsigned short)f2bf(b.y);
    r[6] = (unsigned short)f2bf(b.z); r[7] = (unsigned short)f2bf(b.w);
    *(u16x8*)(out + (size_t)i * 8) = r;
  }
}

// ---- phase 1: bin edges by dst/DSTR, packed word = src | (dstlocal<<17) ---
__global__ __launch_bounds__(P1B) void bin_edges(
    const int* __restrict__ ei, int* __restrict__ bincur,
    int* __restrict__ binbuf, int E, int nbins) {
  __shared__ int cnt[1024];
  __shared__ int cur[1024];
  const int t = threadIdx.x;
  for (int i = t; i < nbins; i += P1B) cnt[i] = 0;
  __syncthreads();
  const int per = (E + gridDim.x - 1) / gridDim.x;
  const int e0 = blockIdx.x * per;
  const int e1 = min(e0 + per, E);
  for (int e = e0 + t; e < e1; e += P1B)
    atomicAdd(&cnt[ei[E + e] / DSTR], 1);
  __syncthreads();
  for (int i = t; i < nbins; i += P1B) {
    const int c = cnt[i];
    cur[i] = c ? atomicAdd(&bincur[i], c) : 0;
  }
  __syncthreads();
  for (int e = e0 + t; e < e1; e += P1B) {
    const int d = ei[E + e];
    const int s = ei[e];
    const int b = d / DSTR;
    const int pos = atomicAdd(&cur[b], 1);
    if (pos < BCAP) binbuf[(size_t)b * BCAP + pos] = s | ((d - b * DSTR) << 17);
  }
}

// ---- GCN degree pre-pass: per-bin LDS count -> global deg ----------------
__global__ __launch_bounds__(256) void deg_from_bins(
    const int* __restrict__ bincur, const int* __restrict__ binbuf,
    int* __restrict__ deg, int N) {
  __shared__ int sdeg[DSTR];
  const int bin = blockIdx.x;
  const int t = threadIdx.x;
  if (t < DSTR) sdeg[t] = 0;
  __syncthreads();
  const int m = min(bincur[bin], BCAP);
  const int* bb = binbuf + (size_t)bin * BCAP;
  for (int j = t; j < m; j += 256) atomicAdd(&sdeg[bb[j] >> 17], 1);
  __syncthreads();
  const int d0 = bin * DSTR;
  if (t < DSTR && d0 + t < N) deg[d0 + t] = sdeg[t];
}

// ---- phase 2: counting-sort by dl in LDS, then per-dst bf16 gather --------
// GCN=0: agg[d] = sum x[src]; writes deg[d].
// GCN=1: agg[d] = sum x[src]*rsqrt(deg[src]+1); deg read-only.
template <int GCN>
__global__ __launch_bounds__(512) void bin_sort_agg(
    const unsigned short* __restrict__ x16, const int* __restrict__ bincur,
    const int* __restrict__ binbuf, const int* __restrict__ deg,
    float* __restrict__ agg, int* __restrict__ degout, int N) {
  __shared__ int scnt[DSTR];
  __shared__ int soff[DSTR + 1];
  __shared__ int scur[DSTR];
  __shared__ int sorted[BCAP];   // 12 KB: src indices grouped by dl
  const int t = threadIdx.x;
  const int bin = blockIdx.x;
  const int d0 = bin * DSTR;
  if (t < DSTR) scnt[t] = 0;
  __syncthreads();
  const int m = min(bincur[bin], BCAP);
  const int* bb = binbuf + (size_t)bin * BCAP;
  for (int j = t; j < m; j += 512) atomicAdd(&scnt[bb[j] >> 17], 1);
  __syncthreads();
  if (t == 0) {
    int run = 0;
    for (int i = 0; i < DSTR; ++i) { soff[i] = run; run += scnt[i]; }
    soff[DSTR] = run;
  }
  __syncthreads();
  if (t < DSTR) scur[t] = soff[t];
  if (!GCN && t < DSTR && d0 + t < N) degout[d0 + t] = scnt[t];
  __syncthreads();
  for (int j = t; j < m; j += 512) {
    const int wd = bb[j];
    const int pos = atomicAdd(&scur[wd >> 17], 1);
    sorted[pos] = wd & 0x1FFFF;
  }
  __syncthreads();
  // gather: one wave per dl; lane = (edge slot 0..7, channel octet 0..7)
  const int lane = t & 63;
  const int w    = t >> 6;
  const int g8   = lane >> 3;
  const int c8   = lane & 7;
  for (int dl = w; dl < DSTR; dl += 8) {
    if (d0 + dl >= N) break;
    const int beg = soff[dl];
    const int cnt = scnt[dl];
    float acc[8] = {0.f, 0.f, 0.f, 0.f, 0.f, 0.f, 0.f, 0.f};
    for (int j0 = 0; j0 < cnt; j0 += 64) {
      const int mm = min(cnt - j0, 64);
      int sv = 0; float cs = 1.0f;
      if (lane < mm) {
        sv = sorted[beg + j0 + lane];
        if (GCN) cs = rsqrtf((float)deg[sv] + 1.0f);
      }
      for (int k = 0; k < mm; k += 32) {   // 32 edges in flight (4 x 8 slots)
        u16x8 vs[4];
        float wsc[4];
#pragma unroll
        for (int tt = 0; tt < 4; ++tt) {
          const int i = k + tt * 8 + g8;
          const int ic = (i < mm) ? i : (mm - 1);
          const int sidx = __shfl(sv, ic, 64);
          const float c = GCN ? __shfl(cs, ic, 64) : 1.0f;
          wsc[tt] = (i < mm) ? c : 0.0f;
          vs[tt] = *(const u16x8*)(x16 + (size_t)sidx * 64 + c8 * 8);
        }
#pragma unroll
        for (int tt = 0; tt < 4; ++tt)
#pragma unroll
          for (int j = 0; j < 8; ++j)
            acc[j] += bf2f(vs[tt][j]) * wsc[tt];
      }
    }
#pragma unroll
    for (int j = 0; j < 8; ++j) {
      acc[j] += __shfl_xor(acc[j], 8, 64);
      acc[j] += __shfl_xor(acc[j], 16, 64);
      acc[j] += __shfl_xor(acc[j], 32, 64);
    }
    if (g8 == 0) {
      float4 o0, o1;
      o0.x = acc[0]; o0.y = acc[1]; o0.z = acc[2]; o0.w = acc[3];
      o1.x = acc[4]; o1.y = acc[5]; o1.z = acc[6]; o1.w = acc[7];
      float* ap = agg + (size_t)(d0 + dl) * 64 + c8 * 8;
      *(float4*)ap = o0;
      *(float4*)(ap + 4) = o1;
    }
  }
}

// ---- fused MFMA epilogues -------------------------------------------------
// MFMA 16x16x32 bf16: A lane holds A[lane&15][8*(lane>>4)+j];
// C/D lane holds D[4*(lane>>4)+i][lane&15].

// SAGE: out = relu(l2norm((A/max(deg,1))@Wl + xdst@Wr + b)); optional bf16 copy
template <int CD>
__global__ __launch_bounds__(256) void sage_ep(
    const float* __restrict__ agg, const int* __restrict__ deg,
    const float* __restrict__ xdst, const float* __restrict__ Wl,
    const float* __restrict__ bias, const float* __restrict__ Wr,
    float* __restrict__ out, unsigned short* __restrict__ out16, int n) {
  const int lane = threadIdx.x & 63;
  const int lr   = lane & 15;
  const int kg   = lane >> 4;
  const int wid  = (blockIdx.x * 256 + threadIdx.x) >> 6;
  const int nw   = (gridDim.x * 256) >> 6;
  bf16x8 wl[2][4], wr[CD / 32][4];
#pragma unroll
  for (int ks = 0; ks < 2; ++ks)
#pragma unroll
    for (int t = 0; t < 4; ++t)
      wl[ks][t] = load_wfrag(Wl, ks * 32 + kg * 8, t * 16 + lr);
#pragma unroll
  for (int ks = 0; ks < CD / 32; ++ks)
#pragma unroll
    for (int t = 0; t < 4; ++t)
      wr[ks][t] = load_wfrag(Wr, ks * 32 + kg * 8, t * 16 + lr);
  const int ntiles = (n + 15) >> 4;
  for (int tile = wid; tile < ntiles; tile += nw) {
    const int r0 = tile << 4;
    const int ra = min(r0 + lr, n - 1);
    const float inva = 1.0f / fmaxf((float)deg[ra], 1.0f);
    f32x4 acc[4];
#pragma unroll
    for (int t = 0; t < 4; ++t) { acc[t][0]=0.f; acc[t][1]=0.f; acc[t][2]=0.f; acc[t][3]=0.f; }
#pragma unroll
    for (int ks = 0; ks < 2; ++ks) {
      const float* ap = agg + (size_t)ra * 64 + ks * 32 + kg * 8;
      const float4 a0 = *(const float4*)ap;
      const float4 a1 = *(const float4*)(ap + 4);
      bf16x8 af;
      af[0] = f2bf(a0.x * inva); af[1] = f2bf(a0.y * inva);
      af[2] = f2bf(a0.z * inva); af[3] = f2bf(a0.w * inva);
      af[4] = f2bf(a1.x * inva); af[5] = f2bf(a1.y * inva);
      af[6] = f2bf(a1.z * inva); af[7] = f2bf(a1.w * inva);
#pragma unroll
      for (int t = 0; t < 4; ++t)
        acc[t] = __builtin_amdgcn_mfma_f32_16x16x32_bf16(af, wl[ks][t], acc[t], 0, 0, 0);
    }
#pragma unroll
    for (int ks = 0; ks < CD / 32; ++ks) {
      const bf16x8 xf = load_bf8(xdst + (size_t)ra * CD + ks * 32 + kg * 8);
#pragma unroll
      for (int t = 0; t < 4; ++t)
        acc[t] = __builtin_amdgcn_mfma_f32_16x16x32_bf16(xf, wr[ks][t], acc[t], 0, 0, 0);
    }
#pragma unroll
    for (int t = 0; t < 4; ++t) {
      const float bv = bias[t * 16 + lr];
#pragma unroll
      for (int i = 0; i < 4; ++i) acc[t][i] += bv;
    }
    float ssi[4];
#pragma unroll
    for (int i = 0; i < 4; ++i) {
      float s = acc[0][i] * acc[0][i] + acc[1][i] * acc[1][i] +
                acc[2][i] * acc[2][i] + acc[3][i] * acc[3][i];
      s += __shfl_xor(s, 1, 64); s += __shfl_xor(s, 2, 64);
      s += __shfl_xor(s, 4, 64); s += __shfl_xor(s, 8, 64);
      ssi[i] = fmaxf(sqrtf(s), 1e-12f);
    }
#pragma unroll
    for (int t = 0; t < 4; ++t)
#pragma unroll
      for (int i = 0; i < 4; ++i) {
        const int r = r0 + kg * 4 + i;
        if (r < n) {
          const float val = fmaxf(acc[t][i] / ssi[i], 0.0f);
          out[(size_t)r * 64 + t * 16 + lr] = val;
          if (out16) out16[(size_t)r * 64 + t * 16 + lr] = (unsigned short)f2bf(val);
        }
      }
  }
}

// GCN: v = relu((A*rsqrt(dd) + x/dd)@W + b), dd = deg+1; BN stats into stats
__global__ __launch_bounds__(256) void gcn_ep(
    const float* __restrict__ agg, const float* __restrict__ x,
    const int* __restrict__ deg, const float* __restrict__ W,
    const float* __restrict__ bias, float* __restrict__ v,
    float* __restrict__ stats, int n) {
  __shared__ float ssum[64], ssq[64];
  if (threadIdx.x < 64) { ssum[threadIdx.x] = 0.f; ssq[threadIdx.x] = 0.f; }
  __syncthreads();
  const int lane = threadIdx.x & 63;
  const int lr   = lane & 15;
  const int kg   = lane >> 4;
  const int wid  = (blockIdx.x * 256 + threadIdx.x) >> 6;
  const int nw   = (gridDim.x * 256) >> 6;
  bf16x8 wf[2][4];
#pragma unroll
  for (int ks = 0; ks < 2; ++ks)
#pragma unroll
    for (int t = 0; t < 4; ++t)
      wf[ks][t] = load_wfrag(W, ks * 32 + kg * 8, t * 16 + lr);
  float psum[4] = {0.f, 0.f, 0.f, 0.f}, psq[4] = {0.f, 0.f, 0.f, 0.f};
  const int ntiles = (n + 15) >> 4;
  for (int tile = wid; tile < ntiles; tile += nw) {
    const int r0 = tile << 4;
    const int ra = min(r0 + lr, n - 1);
    const float dd = (float)deg[ra] + 1.0f;
    const float ca = rsqrtf(dd);
    const float cb = 1.0f / dd;
    f32x4 acc[4];
#pragma unroll
    for (int t = 0; t < 4; ++t) { acc[t][0]=0.f; acc[t][1]=0.f; acc[t][2]=0.f; acc[t][3]=0.f; }
#pragma unroll
    for (int ks = 0; ks < 2; ++ks) {
      const float* ap = agg + (size_t)ra * 64 + ks * 32 + kg * 8;
      const float* xp = x   + (size_t)ra * 64 + ks * 32 + kg * 8;
      const float4 a0 = *(const float4*)ap;
      const float4 a1 = *(const float4*)(ap + 4);
      const float4 x0 = *(const float4*)xp;
      const float4 x1 = *(const float4*)(xp + 4);
      bf16x8 af;
      af[0] = f2bf(a0.x * ca + x0.x * cb); af[1] = f2bf(a0.y * ca + x0.y * cb);
      af[2] = f2bf(a0.z * ca + x0.z * cb); af[3] = f2bf(a0.w * ca + x0.w * cb);
      af[4] = f2bf(a1.x * ca + x1.x * cb); af[5] = f2bf(a1.y * ca + x1.y * cb);
      af[6] = f2bf(a1.z * ca + x1.z * cb); af[7] = f2bf(a1.w * ca + x1.w * cb);
#pragma unroll
      for (int t = 0; t < 4; ++t)
        acc[t] = __builtin_amdgcn_mfma_f32_16x16x32_bf16(af, wf[ks][t], acc[t], 0, 0, 0);
    }
#pragma unroll
    for (int t = 0; t < 4; ++t) {
      const float bv = bias[t * 16 + lr];
#pragma unroll
      for (int i = 0; i < 4; ++i) {
        const int r = r0 + kg * 4 + i;
        if (r < n) {
          const float val = fmaxf(acc[t][i] + bv, 0.0f);
          v[(size_t)r * 64 + t * 16 + lr] = val;
          psum[t] += val;
          psq[t]  += val * val;
        }
      }
    }
  }
#pragma unroll
  for (int t = 0; t < 4; ++t) {
    atomicAdd(&ssum[t * 16 + lr], psum[t]);
    atomicAdd(&ssq[t * 16 + lr], psq[t]);
  }
  __syncthreads();
  if (threadIdx.x < 64) {
    atomicAdd(&stats[threadIdx.x], ssum[threadIdx.x]);
    atomicAdd(&stats[64 + threadIdx.x], ssq[threadIdx.x]);
  }
}

// out = (v - mean) * rsqrt(var + 1e-5) * gam + bet; optional bf16 copy
__global__ __launch_bounds__(BLK) void bn_apply(
    const float* __restrict__ v, const float* __restrict__ stats,
    const float* __restrict__ gam, const float* __restrict__ bet,
    float* __restrict__ out, unsigned short* __restrict__ out16, int n) {
  __shared__ float sm[64], sr[64], sg[64], sbt[64];
  if (threadIdx.x < 64) {
    const float m   = stats[threadIdx.x] / (float)n;
    const float var = stats[64 + threadIdx.x] / (float)n - m * m;
    sm[threadIdx.x]  = m;
    sr[threadIdx.x]  = rsqrtf(var + 1e-5f);
    sg[threadIdx.x]  = gam[threadIdx.x];
    sbt[threadIdx.x] = bet[threadIdx.x];
  }
  __syncthreads();
  const int lane = threadIdx.x & 63;
  const int w    = threadIdx.x >> 6;
  for (int r = blockIdx.x * 4 + w; r < n; r += gridDim.x * 4) {
    const float val =
        (v[(size_t)r * 64 + lane] - sm[lane]) * sr[lane] * sg[lane] + sbt[lane];
    out[(size_t)r * 64 + lane] = val;
    if (out16) out16[(size_t)r * 64 + lane] = (unsigned short)f2bf(val);
  }
}

extern "C" void kernel_launch(void* const* d_in, const int* in_sizes, int n_in,
                              void* d_out, int out_size, void* d_ws, size_t ws_size,
                              hipStream_t stream) {
  const float* game_x  = (const float*)d_in[0];
  const float* state_x = (const float*)d_in[1];
  const float* pc_x    = (const float*)d_in[2];
  const int* ei_vv  = (const int*)d_in[3];
  const int* ei_hvs = (const int*)d_in[4];
  const int* ei_hsv = (const int*)d_in[5];
  const int* ei_ivs = (const int*)d_in[6];
  const int* ei_isv = (const int*)d_in[7];
  const int* ei_ss  = (const int*)d_in[8];
  const int* ei_pp  = (const int*)d_in[9];
  const int* ei_ps  = (const int*)d_in[10];
  const int* ei_sp  = (const int*)d_in[11];
  const float* s_Wl[6], *s_b[6], *s_Wr[6];
  for (int i = 0; i < 6; ++i) {
    s_Wl[i] = (const float*)d_in[12 + 3 * i];
    s_b[i]  = (const float*)d_in[13 + 3 * i];
    s_Wr[i] = (const float*)d_in[14 + 3 * i];
  }
  const float* gcfg_W = (const float*)d_in[30];
  const float* gcfg_b = (const float*)d_in[31];
  const float* gpc_W  = (const float*)d_in[32];
  const float* gpc_b  = (const float*)d_in[33];
  const float* gst_W  = (const float*)d_in[34];
  const float* gst_b  = (const float*)d_in[35];
  const float* bncfg_g = (const float*)d_in[36];
  const float* bncfg_b = (const float*)d_in[37];
  const float* bnpc_g  = (const float*)d_in[38];
  const float* bnpc_b  = (const float*)d_in[39];
  const float* bnst_g  = (const float*)d_in[40];
  const float* bnst_b  = (const float*)d_in[41];

  const int N = in_sizes[1] / 64;   // nodes per type (100000)
  const int E = in_sizes[3] / 2;    // edges per relation (2000000)
  const int NBINS = (N + DSTR - 1) / DSTR;  // 1000

  const size_t nb = (size_t)N * 64;
  // workspace (~102 MB)
  float* A    = (float*)d_ws;                 // nb f32: aggregated features
  float* X    = A + nb;                       // nb f32: rotating temp
  unsigned short* S16  = (unsigned short*)(X + nb);  // nb bf16: state_x
  unsigned short* T16a = S16 + nb;            // nb bf16: rotating (g2,g,s3)
  unsigned short* T16b = T16a + nb;           // nb bf16: rotating (p1,p)
  int*   DEG    = (int*)(T16b + nb);          // N degrees
  int*   BINCUR = DEG + N;                    // NBINS cursors
  int*   BINBUF = BINCUR + NBINS;             // NBINS*BCAP packed edges
  float* STAT   = (float*)(BINBUF + (size_t)NBINS * BCAP);  // 128 BN stats

  float* out_s = (float*)d_out;               // f32 outputs; g/p double as temps
  float* out_g = out_s + nb;
  float* out_p = out_g + nb;

  auto build_bins = [&](const int* ei) {
    hipMemsetAsync(BINCUR, 0, NBINS * sizeof(int), stream);
    bin_edges<<<P1G, P1B, 0, stream>>>(ei, BINCUR, BINBUF, E, NBINS);
  };

  // SAGE: src16 = bf16 gather table; outbuf f32 (+ optional bf16 copy)
  auto run_sage = [&](const int* ei, const unsigned short* src16,
                      const float* xdst, int cd, int wi, float* outbuf,
                      unsigned short* out16) {
    build_bins(ei);
    bin_sort_agg<0><<<NBINS, 512, 0, stream>>>(src16, BINCUR, BINBUF, DEG, A, DEG, N);
    if (cd == 32)
      sage_ep<32><<<1024, 256, 0, stream>>>(A, DEG, xdst, s_Wl[wi], s_b[wi],
                                            s_Wr[wi], outbuf, out16, N);
    else
      sage_ep<64><<<1024, 256, 0, stream>>>(A, DEG, xdst, s_Wl[wi], s_b[wi],
                                            s_Wr[wi], outbuf, out16, N);
  };

  // GCN+BN: src16 = bf16 gather table; x = matching f32 table (self-loop term)
  auto run_gcn_bn = [&](const int* ei, const unsigned short* src16, const float* x,
                        const float* W, const float* b, const float* bng,
                        const float* bnb, float* vbuf, float* outbuf,
                        unsigned short* out16) {
    build_bins(ei);
    deg_from_bins<<<NBINS, 256, 0, stream>>>(BINCUR, BINBUF, DEG, N);
    bin_sort_agg<1><<<NBINS, 512, 0, stream>>>(src16, BINCUR, BINBUF, DEG, A, DEG, N);
    hipMemsetAsync(STAT, 0, 128 * sizeof(float), stream);
    gcn_ep<<<1024, 256, 0, stream>>>(A, x, DEG, W, b, vbuf, STAT, N);
    bn_apply<<<GRID, BLK, 0, stream>>>(vbuf, STAT, bng, bnb, outbuf, out16, N);
  };

  // state_x bf16 copy (used as gather src by sage1/sage2/sage3)
  cvt_bf16<<<2048, 256, 0, stream>>>(state_x, S16, (int)(nb / 8));

  // ---- graph ----
  // g1 = relu(sage1(state->game))                        -> X
  run_sage(ei_hsv, S16, game_x, 32, 0, X, nullptr);
  // g2 = relu(sage2(state->g1))                          -> out_g + T16a
  run_sage(ei_isv, S16, X, 64, 1, out_g, T16a);
  // g  = bn(relu(gcn(g2, v_v)))   v->X                   -> out_g + T16a
  run_gcn_bn(ei_vv, T16a, out_g, gcfg_W, gcfg_b, bncfg_g, bncfg_b, X, out_g, T16a);
  // p1 = relu(sage3(state->pc))                          -> X + T16b
  run_sage(ei_sp, S16, pc_x, 32, 2, X, T16b);
  // p  = bn(relu(gcn(p1, pc_pc))) v->out_p (inplace BN)  -> out_p + T16b
  run_gcn_bn(ei_pp, T16b, X, gpc_W, gpc_b, bnpc_g, bnpc_b, out_p, out_p, T16b);
  // s1 = relu(sage4(g->state))                           -> X
  run_sage(ei_hvs, T16a, state_x, 64, 3, X, nullptr);
  // s2 = relu(sage5(g->s1))                              -> out_s
  run_sage(ei_ivs, T16a, X, 64, 4, out_s, nullptr);
  // s3 = relu(sage6(p->s2))                              -> X + T16a
  run_sage(ei_ps, T16b, out_s, 64, 5, X, T16a);
  // s  = bn(relu(gcn(s3, s_s)))   v->out_s (inplace BN)  -> out_s
  run_gcn_bn(ei_ss, T16a, X, gst_W, gst_b, bnst_g, bnst_b, out_s, out_s, nullptr);
}

// Round 11
// 1088.749 us; speedup vs baseline: 6.4003x; 1.1389x over previous
//
#include <hip/hip_runtime.h>
#include <hip/hip_bf16.h>

// ---------------------------------------------------------------------------
// Hetero-GNN forward: 6 SAGEConv (mean aggr, L2-norm) + 3 GCNConv + 3 BN.
// Round 11: bin_edges occupancy fix — 256 blocks x 1024 threads (was 256:
// 1 block/CU, 9% occupancy, latency-bound). Global bincur atomics stay at
// 256k. Structure otherwise = round 10 (bf16 gather tables, per-bin counting
// sort, MFMA epilogues).
// ---------------------------------------------------------------------------

#define GRID   2048
#define BLK    256
#define DSTR   100    // dsts per bin
#define BCAP   3072   // bin capacity (mean 2000)
#define P1G    256    // phase-1 blocks (bounds global atomics at P1G*nbins)
#define P1B    1024   // phase-1 threads (16 waves/CU when 1 block/CU)

typedef __attribute__((ext_vector_type(8))) short bf16x8;          // MFMA A/B
typedef __attribute__((ext_vector_type(4))) float f32x4;           // MFMA C/D
typedef __attribute__((ext_vector_type(8))) unsigned short u16x8;  // bf16 row oct

__device__ inline short f2bf(float f) {
  __hip_bfloat16 h = __float2bfloat16(f);
  return *reinterpret_cast<short*>(&h);
}

__device__ inline float bf2f(unsigned short u) {
  union { unsigned int i; float f; } x;
  x.i = ((unsigned int)u) << 16;
  return x.f;
}

__device__ inline bf16x8 load_bf8(const float* p) {
  const float4 a = *(const float4*)p;
  const float4 b = *(const float4*)(p + 4);
  bf16x8 r;
  r[0] = f2bf(a.x); r[1] = f2bf(a.y); r[2] = f2bf(a.z); r[3] = f2bf(a.w);
  r[4] = f2bf(b.x); r[5] = f2bf(b.y); r[6] = f2bf(b.z); r[7] = f2bf(b.w);
  return r;
}

// B-fragment: lane holds W[kbase+j][col], j=0..7
__device__ inline bf16x8 load_wfrag(const float* W, int kbase, int col) {
  bf16x8 r;
#pragma unroll
  for (int j = 0; j < 8; ++j) r[j] = f2bf(W[(kbase + j) * 64 + col]);
  return r;
}

// ---- f32 -> bf16 table conversion (for gather sources) --------------------
__global__ __launch_bounds__(256) void cvt_bf16(
    const float* __restrict__ in, unsigned short* __restrict__ out, int n8) {
  for (int i = blockIdx.x * 256 + threadIdx.x; i < n8; i += gridDim.x * 256) {
    const float4 a = *(const float4*)(in + (size_t)i * 8);
    const float4 b = *(const float4*)(in + (size_t)i * 8 + 4);
    u16x8 r;
    r[0] = (unsigned short)f2bf(a.x); r[1] = (unsigned short)f2bf(a.y);
    r[2] = (unsigned short)f2bf(a.z); r[3] = (unsigned short)f2bf(a.w);
    r[4] = (unsigned short)f2bf(b.x); r[5] = (unsigned short)f2bf(b.y);
    r[6] = (unsigned short)f2bf(b.z); r[7] = (unsigned short)f2bf(b.w);
    *(u16x8*)(out + (size_t)i * 8) = r;
  }
}

// ---- phase 1: bin edges by dst/DSTR, packed word = src | (dstlocal<<17) ---
__global__ __launch_bounds__(P1B) void bin_edges(
    const int* __restrict__ ei, int* __restrict__ bincur,
    int* __restrict__ binbuf, int E, int nbins) {
  __shared__ int cnt[1024];
  __shared__ int cur[1024];
  const int t = threadIdx.x;
  for (int i = t; i < nbins; i += P1B) cnt[i] = 0;
  __syncthreads();
  const int per = (E + gridDim.x - 1) / gridDim.x;
  const int e0 = blockIdx.x * per;
  const int e1 = min(e0 + per, E);
  for (int e = e0 + t; e < e1; e += P1B)
    atomicAdd(&cnt[ei[E + e] / DSTR], 1);
  __syncthreads();
  for (int i = t; i < nbins; i += P1B) {
    const int c = cnt[i];
    cur[i] = c ? atomicAdd(&bincur[i], c) : 0;
  }
  __syncthreads();
  for (int e = e0 + t; e < e1; e += P1B) {
    const int d = ei[E + e];
    const int s = ei[e];
    const int b = d / DSTR;
    const int pos = atomicAdd(&cur[b], 1);
    if (pos < BCAP) binbuf[(size_t)b * BCAP + pos] = s | ((d - b * DSTR) << 17);
  }
}

// ---- GCN degree pre-pass: per-bin LDS count -> global deg ----------------
__global__ __launch_bounds__(256) void deg_from_bins(
    const int* __restrict__ bincur, const int* __restrict__ binbuf,
    int* __restrict__ deg, int N) {
  __shared__ int sdeg[DSTR];
  const int bin = blockIdx.x;
  const int t = threadIdx.x;
  if (t < DSTR) sdeg[t] = 0;
  __syncthreads();
  const int m = min(bincur[bin], BCAP);
  const int* bb = binbuf + (size_t)bin * BCAP;
  for (int j = t; j < m; j += 256) atomicAdd(&sdeg[bb[j] >> 17], 1);
  __syncthreads();
  const int d0 = bin * DSTR;
  if (t < DSTR && d0 + t < N) deg[d0 + t] = sdeg[t];
}

// ---- phase 2: counting-sort by dl in LDS, then per-dst bf16 gather --------
// GCN=0: agg[d] = sum x[src]; writes deg[d].
// GCN=1: agg[d] = sum x[src]*rsqrt(deg[src]+1); deg read-only.
template <int GCN>
__global__ __launch_bounds__(512) void bin_sort_agg(
    const unsigned short* __restrict__ x16, const int* __restrict__ bincur,
    const int* __restrict__ binbuf, const int* __restrict__ deg,
    float* __restrict__ agg, int* __restrict__ degout, int N) {
  __shared__ int scnt[DSTR];
  __shared__ int soff[DSTR + 1];
  __shared__ int scur[DSTR];
  __shared__ int sorted[BCAP];   // 12 KB: src indices grouped by dl
  const int t = threadIdx.x;
  const int bin = blockIdx.x;
  const int d0 = bin * DSTR;
  if (t < DSTR) scnt[t] = 0;
  __syncthreads();
  const int m = min(bincur[bin], BCAP);
  const int* bb = binbuf + (size_t)bin * BCAP;
  for (int j = t; j < m; j += 512) atomicAdd(&scnt[bb[j] >> 17], 1);
  __syncthreads();
  if (t == 0) {
    int run = 0;
    for (int i = 0; i < DSTR; ++i) { soff[i] = run; run += scnt[i]; }
    soff[DSTR] = run;
  }
  __syncthreads();
  if (t < DSTR) scur[t] = soff[t];
  if (!GCN && t < DSTR && d0 + t < N) degout[d0 + t] = scnt[t];
  __syncthreads();
  for (int j = t; j < m; j += 512) {
    const int wd = bb[j];
    const int pos = atomicAdd(&scur[wd >> 17], 1);
    sorted[pos] = wd & 0x1FFFF;
  }
  __syncthreads();
  // gather: one wave per dl; lane = (edge slot 0..7, channel octet 0..7)
  const int lane = t & 63;
  const int w    = t >> 6;
  const int g8   = lane >> 3;
  const int c8   = lane & 7;
  for (int dl = w; dl < DSTR; dl += 8) {
    if (d0 + dl >= N) break;
    const int beg = soff[dl];
    const int cnt = scnt[dl];
    float acc[8] = {0.f, 0.f, 0.f, 0.f, 0.f, 0.f, 0.f, 0.f};
    for (int j0 = 0; j0 < cnt; j0 += 64) {
      const int mm = min(cnt - j0, 64);
      int sv = 0; float cs = 1.0f;
      if (lane < mm) {
        sv = sorted[beg + j0 + lane];
        if (GCN) cs = rsqrtf((float)deg[sv] + 1.0f);
      }
      for (int k = 0; k < mm; k += 32) {   // 32 edges in flight (4 x 8 slots)
        u16x8 vs[4];
        float wsc[4];
#pragma unroll
        for (int tt = 0; tt < 4; ++tt) {
          const int i = k + tt * 8 + g8;
          const int ic = (i < mm) ? i : (mm - 1);
          const int sidx = __shfl(sv, ic, 64);
          const float c = GCN ? __shfl(cs, ic, 64) : 1.0f;
          wsc[tt] = (i < mm) ? c : 0.0f;
          vs[tt] = *(const u16x8*)(x16 + (size_t)sidx * 64 + c8 * 8);
        }
#pragma unroll
        for (int tt = 0; tt < 4; ++tt)
#pragma unroll
          for (int j = 0; j < 8; ++j)
            acc[j] += bf2f(vs[tt][j]) * wsc[tt];
      }
    }
#pragma unroll
    for (int j = 0; j < 8; ++j) {
      acc[j] += __shfl_xor(acc[j], 8, 64);
      acc[j] += __shfl_xor(acc[j], 16, 64);
      acc[j] += __shfl_xor(acc[j], 32, 64);
    }
    if (g8 == 0) {
      float4 o0, o1;
      o0.x = acc[0]; o0.y = acc[1]; o0.z = acc[2]; o0.w = acc[3];
      o1.x = acc[4]; o1.y = acc[5]; o1.z = acc[6]; o1.w = acc[7];
      float* ap = agg + (size_t)(d0 + dl) * 64 + c8 * 8;
      *(float4*)ap = o0;
      *(float4*)(ap + 4) = o1;
    }
  }
}

// ---- fused MFMA epilogues -------------------------------------------------
// MFMA 16x16x32 bf16: A lane holds A[lane&15][8*(lane>>4)+j];
// C/D lane holds D[4*(lane>>4)+i][lane&15].

// SAGE: out = relu(l2norm((A/max(deg,1))@Wl + xdst@Wr + b)); optional bf16 copy
template <int CD>
__global__ __launch_bounds__(256) void sage_ep(
    const float* __restrict__ agg, const int* __restrict__ deg,
    const float* __restrict__ xdst, const float* __restrict__ Wl,
    const float* __restrict__ bias, const float* __restrict__ Wr,
    float* __restrict__ out, unsigned short* __restrict__ out16, int n) {
  const int lane = threadIdx.x & 63;
  const int lr   = lane & 15;
  const int kg   = lane >> 4;
  const int wid  = (blockIdx.x * 256 + threadIdx.x) >> 6;
  const int nw   = (gridDim.x * 256) >> 6;
  bf16x8 wl[2][4], wr[CD / 32][4];
#pragma unroll
  for (int ks = 0; ks < 2; ++ks)
#pragma unroll
    for (int t = 0; t < 4; ++t)
      wl[ks][t] = load_wfrag(Wl, ks * 32 + kg * 8, t * 16 + lr);
#pragma unroll
  for (int ks = 0; ks < CD / 32; ++ks)
#pragma unroll
    for (int t = 0; t < 4; ++t)
      wr[ks][t] = load_wfrag(Wr, ks * 32 + kg * 8, t * 16 + lr);
  const int ntiles = (n + 15) >> 4;
  for (int tile = wid; tile < ntiles; tile += nw) {
    const int r0 = tile << 4;
    const int ra = min(r0 + lr, n - 1);
    const float inva = 1.0f / fmaxf((float)deg[ra], 1.0f);
    f32x4 acc[4];
#pragma unroll
    for (int t = 0; t < 4; ++t) { acc[t][0]=0.f; acc[t][1]=0.f; acc[t][2]=0.f; acc[t][3]=0.f; }
#pragma unroll
    for (int ks = 0; ks < 2; ++ks) {
      const float* ap = agg + (size_t)ra * 64 + ks * 32 + kg * 8;
      const float4 a0 = *(const float4*)ap;
      const float4 a1 = *(const float4*)(ap + 4);
      bf16x8 af;
      af[0] = f2bf(a0.x * inva); af[1] = f2bf(a0.y * inva);
      af[2] = f2bf(a0.z * inva); af[3] = f2bf(a0.w * inva);
      af[4] = f2bf(a1.x * inva); af[5] = f2bf(a1.y * inva);
      af[6] = f2bf(a1.z * inva); af[7] = f2bf(a1.w * inva);
#pragma unroll
      for (int t = 0; t < 4; ++t)
        acc[t] = __builtin_amdgcn_mfma_f32_16x16x32_bf16(af, wl[ks][t], acc[t], 0, 0, 0);
    }
#pragma unroll
    for (int ks = 0; ks < CD / 32; ++ks) {
      const bf16x8 xf = load_bf8(xdst + (size_t)ra * CD + ks * 32 + kg * 8);
#pragma unroll
      for (int t = 0; t < 4; ++t)
        acc[t] = __builtin_amdgcn_mfma_f32_16x16x32_bf16(xf, wr[ks][t], acc[t], 0, 0, 0);
    }
#pragma unroll
    for (int t = 0; t < 4; ++t) {
      const float bv = bias[t * 16 + lr];
#pragma unroll
      for (int i = 0; i < 4; ++i) acc[t][i] += bv;
    }
    float ssi[4];
#pragma unroll
    for (int i = 0; i < 4; ++i) {
      float s = acc[0][i] * acc[0][i] + acc[1][i] * acc[1][i] +
                acc[2][i] * acc[2][i] + acc[3][i] * acc[3][i];
      s += __shfl_xor(s, 1, 64); s += __shfl_xor(s, 2, 64);
      s += __shfl_xor(s, 4, 64); s += __shfl_xor(s, 8, 64);
      ssi[i] = fmaxf(sqrtf(s), 1e-12f);
    }
#pragma unroll
    for (int t = 0; t < 4; ++t)
#pragma unroll
      for (int i = 0; i < 4; ++i) {
        const int r = r0 + kg * 4 + i;
        if (r < n) {
          const float val = fmaxf(acc[t][i] / ssi[i], 0.0f);
          out[(size_t)r * 64 + t * 16 + lr] = val;
          if (out16) out16[(size_t)r * 64 + t * 16 + lr] = (unsigned short)f2bf(val);
        }
      }
  }
}

// GCN: v = relu((A*rsqrt(dd) + x/dd)@W + b), dd = deg+1; BN stats into stats
__global__ __launch_bounds__(256) void gcn_ep(
    const float* __restrict__ agg, const float* __restrict__ x,
    const int* __restrict__ deg, const float* __restrict__ W,
    const float* __restrict__ bias, float* __restrict__ v,
    float* __restrict__ stats, int n) {
  __shared__ float ssum[64], ssq[64];
  if (threadIdx.x < 64) { ssum[threadIdx.x] = 0.f; ssq[threadIdx.x] = 0.f; }
  __syncthreads();
  const int lane = threadIdx.x & 63;
  const int lr   = lane & 15;
  const int kg   = lane >> 4;
  const int wid  = (blockIdx.x * 256 + threadIdx.x) >> 6;
  const int nw   = (gridDim.x * 256) >> 6;
  bf16x8 wf[2][4];
#pragma unroll
  for (int ks = 0; ks < 2; ++ks)
#pragma unroll
    for (int t = 0; t < 4; ++t)
      wf[ks][t] = load_wfrag(W, ks * 32 + kg * 8, t * 16 + lr);
  float psum[4] = {0.f, 0.f, 0.f, 0.f}, psq[4] = {0.f, 0.f, 0.f, 0.f};
  const int ntiles = (n + 15) >> 4;
  for (int tile = wid; tile < ntiles; tile += nw) {
    const int r0 = tile << 4;
    const int ra = min(r0 + lr, n - 1);
    const float dd = (float)deg[ra] + 1.0f;
    const float ca = rsqrtf(dd);
    const float cb = 1.0f / dd;
    f32x4 acc[4];
#pragma unroll
    for (int t = 0; t < 4; ++t) { acc[t][0]=0.f; acc[t][1]=0.f; acc[t][2]=0.f; acc[t][3]=0.f; }
#pragma unroll
    for (int ks = 0; ks < 2; ++ks) {
      const float* ap = agg + (size_t)ra * 64 + ks * 32 + kg * 8;
      const float* xp = x   + (size_t)ra * 64 + ks * 32 + kg * 8;
      const float4 a0 = *(const float4*)ap;
      const float4 a1 = *(const float4*)(ap + 4);
      const float4 x0 = *(const float4*)xp;
      const float4 x1 = *(const float4*)(xp + 4);
      bf16x8 af;
      af[0] = f2bf(a0.x * ca + x0.x * cb); af[1] = f2bf(a0.y * ca + x0.y * cb);
      af[2] = f2bf(a0.z * ca + x0.z * cb); af[3] = f2bf(a0.w * ca + x0.w * cb);
      af[4] = f2bf(a1.x * ca + x1.x * cb); af[5] = f2bf(a1.y * ca + x1.y * cb);
      af[6] = f2bf(a1.z * ca + x1.z * cb); af[7] = f2bf(a1.w * ca + x1.w * cb);
#pragma unroll
      for (int t = 0; t < 4; ++t)
        acc[t] = __builtin_amdgcn_mfma_f32_16x16x32_bf16(af, wf[ks][t], acc[t], 0, 0, 0);
    }
#pragma unroll
    for (int t = 0; t < 4; ++t) {
      const float bv = bias[t * 16 + lr];
#pragma unroll
      for (int i = 0; i < 4; ++i) {
        const int r = r0 + kg * 4 + i;
        if (r < n) {
          const float val = fmaxf(acc[t][i] + bv, 0.0f);
          v[(size_t)r * 64 + t * 16 + lr] = val;
          psum[t] += val;
          psq[t]  += val * val;
        }
      }
    }
  }
#pragma unroll
  for (int t = 0; t < 4; ++t) {
    atomicAdd(&ssum[t * 16 + lr], psum[t]);
    atomicAdd(&ssq[t * 16 + lr], psq[t]);
  }
  __syncthreads();
  if (threadIdx.x < 64) {
    atomicAdd(&stats[threadIdx.x], ssum[threadIdx.x]);
    atomicAdd(&stats[64 + threadIdx.x], ssq[threadIdx.x]);
  }
}

// out = (v - mean) * rsqrt(var + 1e-5) * gam + bet; optional bf16 copy
__global__ __launch_bounds__(BLK) void bn_apply(
    const float* __restrict__ v, const float* __restrict__ stats,
    const float* __restrict__ gam, const float* __restrict__ bet,
    float* __restrict__ out, unsigned short* __restrict__ out16, int n) {
  __shared__ float sm[64], sr[64], sg[64], sbt[64];
  if (threadIdx.x < 64) {
    const float m   = stats[threadIdx.x] / (float)n;
    const float var = stats[64 + threadIdx.x] / (float)n - m * m;
    sm[threadIdx.x]  = m;
    sr[threadIdx.x]  = rsqrtf(var + 1e-5f);
    sg[threadIdx.x]  = gam[threadIdx.x];
    sbt[threadIdx.x] = bet[threadIdx.x];
  }
  __syncthreads();
  const int lane = threadIdx.x & 63;
  const int w    = threadIdx.x >> 6;
  for (int r = blockIdx.x * 4 + w; r < n; r += gridDim.x * 4) {
    const float val =
        (v[(size_t)r * 64 + lane] - sm[lane]) * sr[lane] * sg[lane] + sbt[lane];
    out[(size_t)r * 64 + lane] = val;
    if (out16) out16[(size_t)r * 64 + lane] = (unsigned short)f2bf(val);
  }
}

extern "C" void kernel_launch(void* const* d_in, const int* in_sizes, int n_in,
                              void* d_out, int out_size, void* d_ws, size_t ws_size,
                              hipStream_t stream) {
  const float* game_x  = (const float*)d_in[0];
  const float* state_x = (const float*)d_in[1];
  const float* pc_x    = (const float*)d_in[2];
  const int* ei_vv  = (const int*)d_in[3];
  const int* ei_hvs = (const int*)d_in[4];
  const int* ei_hsv = (const int*)d_in[5];
  const int* ei_ivs = (const int*)d_in[6];
  const int* ei_isv = (const int*)d_in[7];
  const int* ei_ss  = (const int*)d_in[8];
  const int* ei_pp  = (const int*)d_in[9];
  const int* ei_ps  = (const int*)d_in[10];
  const int* ei_sp  = (const int*)d_in[11];
  const float* s_Wl[6], *s_b[6], *s_Wr[6];
  for (int i = 0; i < 6; ++i) {
    s_Wl[i] = (const float*)d_in[12 + 3 * i];
    s_b[i]  = (const float*)d_in[13 + 3 * i];
    s_Wr[i] = (const float*)d_in[14 + 3 * i];
  }
  const float* gcfg_W = (const float*)d_in[30];
  const float* gcfg_b = (const float*)d_in[31];
  const float* gpc_W  = (const float*)d_in[32];
  const float* gpc_b  = (const float*)d_in[33];
  const float* gst_W  = (const float*)d_in[34];
  const float* gst_b  = (const float*)d_in[35];
  const float* bncfg_g = (const float*)d_in[36];
  const float* bncfg_b = (const float*)d_in[37];
  const float* bnpc_g  = (const float*)d_in[38];
  const float* bnpc_b  = (const float*)d_in[39];
  const float* bnst_g  = (const float*)d_in[40];
  const float* bnst_b  = (const float*)d_in[41];

  const int N = in_sizes[1] / 64;   // nodes per type (100000)
  const int E = in_sizes[3] / 2;    // edges per relation (2000000)
  const int NBINS = (N + DSTR - 1) / DSTR;  // 1000

  const size_t nb = (size_t)N * 64;
  // workspace (~102 MB)
  float* A    = (float*)d_ws;                 // nb f32: aggregated features
  float* X    = A + nb;                       // nb f32: rotating temp
  unsigned short* S16  = (unsigned short*)(X + nb);  // nb bf16: state_x
  unsigned short* T16a = S16 + nb;            // nb bf16: rotating (g2,g,s3)
  unsigned short* T16b = T16a + nb;           // nb bf16: rotating (p1,p)
  int*   DEG    = (int*)(T16b + nb);          // N degrees
  int*   BINCUR = DEG + N;                    // NBINS cursors
  int*   BINBUF = BINCUR + NBINS;             // NBINS*BCAP packed edges
  float* STAT   = (float*)(BINBUF + (size_t)NBINS * BCAP);  // 128 BN stats

  float* out_s = (float*)d_out;               // f32 outputs; g/p double as temps
  float* out_g = out_s + nb;
  float* out_p = out_g + nb;

  auto build_bins = [&](const int* ei) {
    hipMemsetAsync(BINCUR, 0, NBINS * sizeof(int), stream);
    bin_edges<<<P1G, P1B, 0, stream>>>(ei, BINCUR, BINBUF, E, NBINS);
  };

  // SAGE: src16 = bf16 gather table; outbuf f32 (+ optional bf16 copy)
  auto run_sage = [&](const int* ei, const unsigned short* src16,
                      const float* xdst, int cd, int wi, float* outbuf,
                      unsigned short* out16) {
    build_bins(ei);
    bin_sort_agg<0><<<NBINS, 512, 0, stream>>>(src16, BINCUR, BINBUF, DEG, A, DEG, N);
    if (cd == 32)
      sage_ep<32><<<1024, 256, 0, stream>>>(A, DEG, xdst, s_Wl[wi], s_b[wi],
                                            s_Wr[wi], outbuf, out16, N);
    else
      sage_ep<64><<<1024, 256, 0, stream>>>(A, DEG, xdst, s_Wl[wi], s_b[wi],
                                            s_Wr[wi], outbuf, out16, N);
  };

  // GCN+BN: src16 = bf16 gather table; x = matching f32 table (self-loop term)
  auto run_gcn_bn = [&](const int* ei, const unsigned short* src16, const float* x,
                        const float* W, const float* b, const float* bng,
                        const float* bnb, float* vbuf, float* outbuf,
                        unsigned short* out16) {
    build_bins(ei);
    deg_from_bins<<<NBINS, 256, 0, stream>>>(BINCUR, BINBUF, DEG, N);
    bin_sort_agg<1><<<NBINS, 512, 0, stream>>>(src16, BINCUR, BINBUF, DEG, A, DEG, N);
    hipMemsetAsync(STAT, 0, 128 * sizeof(float), stream);
    gcn_ep<<<1024, 256, 0, stream>>>(A, x, DEG, W, b, vbuf, STAT, N);
    bn_apply<<<GRID, BLK, 0, stream>>>(vbuf, STAT, bng, bnb, outbuf, out16, N);
  };

  // state_x bf16 copy (used as gather src by sage1/sage2/sage3)
  cvt_bf16<<<2048, 256, 0, stream>>>(state_x, S16, (int)(nb / 8));

  // ---- graph ----
  // g1 = relu(sage1(state->game))                        -> X
  run_sage(ei_hsv, S16, game_x, 32, 0, X, nullptr);
  // g2 = relu(sage2(state->g1))                          -> out_g + T16a
  run_sage(ei_isv, S16, X, 64, 1, out_g, T16a);
  // g  = bn(relu(gcn(g2, v_v)))   v->X                   -> out_g + T16a
  run_gcn_bn(ei_vv, T16a, out_g, gcfg_W, gcfg_b, bncfg_g, bncfg_b, X, out_g, T16a);
  // p1 = relu(sage3(state->pc))                          -> X + T16b
  run_sage(ei_sp, S16, pc_x, 32, 2, X, T16b);
  // p  = bn(relu(gcn(p1, pc_pc))) v->out_p (inplace BN)  -> out_p + T16b
  run_gcn_bn(ei_pp, T16b, X, gpc_W, gpc_b, bnpc_g, bnpc_b, out_p, out_p, T16b);
  // s1 = relu(sage4(g->state))                           -> X
  run_sage(ei_hvs, T16a, state_x, 64, 3, X, nullptr);
  // s2 = relu(sage5(g->s1))                              -> out_s
  run_sage(ei_ivs, T16a, X, 64, 4, out_s, nullptr);
  // s3 = relu(sage6(p->s2))                              -> X + T16a
  run_sage(ei_ps, T16b, out_s, 64, 5, X, T16a);
  // s  = bn(relu(gcn(s3, s_s)))   v->out_s (inplace BN)  -> out_s
  run_gcn_bn(ei_ss, T16a, X, gst_W, gst_b, bnst_g, bnst_b, out_s, out_s, nullptr);
}